// Round 5
// baseline (363.614 us; speedup 1.0000x reference)
//
#include <hip/hip_runtime.h>

// PostNormBoth: T=256-step recurrence, B=512 chains, H=256.
// R6 = R5 resubmit (previous bench died to an infra container failure, no
// kernel data). Structure: R1 chassis (256 blocks x 512 thr, f32 LDS memory
// slots, 1 block/CU) with the step pipeline cut to 2 barriers:
//  - waves 0/1 own batch rows 0/1 entirely (4 hids/lane) -> LN stats are
//    pure in-wave DPP; the s_red LDS roundtrip and its barrier are deleted.
//    Waves 2-7 only run MFMA + barriers.
//  - v(t+1) = base + coef*hn with base/coef computed BEFORE the MFMA
//    barrier (ctx = ctxA(old window, admit) + hn*wdot). Post-LN critical
//    path = 1 fma + cvt + ds_write. Window scatter/slide/retire + next-step
//    prefetches sit off the critical path, f32x4-vectorized.

#define TT 256

typedef __bf16 bf16x8 __attribute__((ext_vector_type(8)));
typedef __bf16 bf16x4 __attribute__((ext_vector_type(4)));
typedef float  f32x4  __attribute__((ext_vector_type(4)));

__device__ __forceinline__ float fast_tanh(float x) {
    float e = __expf(2.f * x);
    return 1.f - __fdividef(2.f, e + 1.f);
}

// v += dpp(v); old=0 + bound_ctrl so masked lanes add 0.
template<int CTRL, int RM>
__device__ __forceinline__ float dpp_add(float v) {
    int t = __builtin_amdgcn_update_dpp(0, __float_as_int(v), CTRL, RM, 0xf, true);
    return v + __int_as_float(t);
}
// 64-lane sum, result valid in ALL lanes.
__device__ __forceinline__ float wave_sum_all(float v) {
    v = dpp_add<0xB1,  0xf>(v);   // xor1 (quad_perm)
    v = dpp_add<0x4E,  0xf>(v);   // xor2 (quad_perm)
    v = dpp_add<0x141, 0xf>(v);   // 8-group (half mirror)
    v = dpp_add<0x140, 0xf>(v);   // 16-group (row mirror)
    {   int t = __builtin_amdgcn_ds_swizzle(__float_as_int(v), 0x401F); // xor16
        v += __int_as_float(t); }
    v += __shfl_xor(v, 32, 64);   // xor32
    return v;
}

// ---- dynamic LDS layout (bytes) ----
// s_mem [2][64][256] f32 :      0  (131072)
// s_x   [2][256]     f32 : 131072  (2048)
// s_y   [2][256]     f32 : 133120  (2048)
// s_v   [2][288]     bf16: 135168  (1152)
// s_wt  [64][8]      f32 : 136320  (2048)
#define SMEM_BYTES 138368

__global__ __launch_bounds__(512, 2)
void postnorm_kernel(const float* __restrict__ x,
                     const float* __restrict__ W_embed,
                     const float* __restrict__ b_embed,
                     const float* __restrict__ W_update,
                     const float* __restrict__ b_update,
                     const float* __restrict__ gamma,
                     const float* __restrict__ beta,
                     const float* __restrict__ W_out,
                     const float* __restrict__ b_out,
                     const float* __restrict__ ctx_s,
                     float* __restrict__ out)
{
    extern __shared__ __align__(16) char smem[];
    float*  s_mem = (float*)(smem);
    float*  s_x   = (float*)(smem + 131072);
    float*  s_y   = (float*)(smem + 133120);
    __bf16* s_v   = (__bf16*)(smem + 135168);
    float*  s_wt  = (float*)(smem + 136320);

    const int tid  = threadIdx.x;
    const int wave = tid >> 6;      // waves 0/1 own rows 0/1; 2-7 helpers
    const int lane = tid & 63;
    const int bn   = lane & 15;     // MFMA col; real batch only for <2
    const int quad = lane >> 4;
    const int r0   = blockIdx.x * 2;
    const int n    = wave;          // row index (meaningful for wave<2)
    const int h0   = lane << 2;     // 4 hidden columns per lane (wave<2)

    // ---- init ----
    {   f32x4 z = {0.f, 0.f, 0.f, 0.f};
        f32x4* p = (f32x4*)s_mem;
        #pragma unroll
        for (int k = 0; k < 16; ++k) p[tid + k * 512] = z;
    }
    s_x[tid] = x[(r0 + (tid >> 8)) * TT + (tid & 255)];

    // weight table: pointer is t&63; row padded to 8 floats
    if (tid < 64) {
        float wv[5]; float ssum = 0.f;
        #pragma unroll
        for (int k = 0; k < 5; ++k) {
            int idx = (tid + k - 2) & 63;            // wrapped index
            float d = (float)idx - (float)tid;       // delta AFTER wrap
            wv[k] = expf(-(d * d) * 0.125f);         // TAU=8
            ssum += wv[k];
        }
        #pragma unroll
        for (int k = 0; k < 5; ++k) s_wt[tid * 8 + k] = wv[k] / ssum;
    }

    const float csv = 1.f / (1.f + expf(-ctx_s[0]));

    // ---- W_update -> bf16 MFMA A-fragments resident in VGPRs ----
    bf16x8 wfa[2][8];
    #pragma unroll
    for (int mt = 0; mt < 2; ++mt) {
        #pragma unroll
        for (int kt = 0; kt < 8; ++kt) {
            const float* wp = W_update + (wave * 32 + mt * 16 + bn) * 256
                                       + kt * 32 + quad * 8;
            f32x4 a = *(const f32x4*)wp;
            f32x4 b = *(const f32x4*)(wp + 4);
            bf16x8 f;
            f[0] = (__bf16)a[0]; f[1] = (__bf16)a[1];
            f[2] = (__bf16)a[2]; f[3] = (__bf16)a[3];
            f[4] = (__bf16)b[0]; f[5] = (__bf16)b[1];
            f[6] = (__bf16)b[2]; f[7] = (__bf16)b[3];
            wfa[mt][kt] = f;
        }
    }

    __syncthreads();   // s_x, s_wt, s_mem visible

    f32x4 z4 = {0.f, 0.f, 0.f, 0.f};
    f32x4 we = z4, be = z4, bu = z4, gm = z4, bt = z4;
    f32x4 nw = z4, nf = z4, hn = z4;
    f32x4 wr0 = z4, wr1 = z4, wr2 = z4, wr3 = z4, wr4 = z4;
    float wt0 = 0.f, wt1 = 0.f, wt2 = 0.f, wt3 = 0.f, wt4 = 0.f;
    float nw4 = 0.f, xn = 0.f;
    float* mcol = s_mem;

    if (wave < 2) {
        we = *(const f32x4*)(W_embed  + h0);
        be = *(const f32x4*)(b_embed  + h0);
        bu = *(const f32x4*)(b_update + h0);
        gm = *(const f32x4*)(gamma    + h0);
        bt = *(const f32x4*)(beta     + h0);
        mcol = s_mem + (n << 14) + h0;
        // v(t=0): memory==0, h==0 -> v = inp
        float x0 = s_x[n * 256];
        bf16x4 vv;
        #pragma unroll
        for (int j = 0; j < 4; ++j)
            vv[j] = (__bf16)fast_tanh(x0 * we[j] + be[j]);
        *(bf16x4*)(s_v + n * 288 + h0) = vv;
        // pointer-0 weights + step-0 prefetches
        wt0 = s_wt[0]; wt1 = s_wt[1]; wt2 = s_wt[2]; wt3 = s_wt[3]; wt4 = s_wt[4];
        nw  = *(const f32x4*)(s_wt + 8);   // pointer-1 weights
        nw4 = s_wt[12];
        xn  = s_x[n * 256 + 1];
    }
    __syncthreads();   // v(0) visible

    // broadcast B-frag source; row stride 288 bf16 keeps rows bank-disjoint
    const __bf16* vsrc = s_v + (bn & 1) * 288 + quad * 8;

    #pragma unroll 1
    for (int t = 0; t < TT; ++t) {
        // --- pre-phase (wave<2): everything not depending on hn(t),
        //     hidden under the MFMA phase ---
        f32x4 base = z4;
        float coef = 1.f;
        if (wave < 2) {
            float wdot = (nw[0] * wt1 + nw[1] * wt2)
                       + (nw[2] * wt3 + nw[3] * wt4);
            coef = 1.f + csv * wdot;
            #pragma unroll
            for (int j = 0; j < 4; ++j) {
                float ctxA = ((nw[0] * wr1[j] + nw[1] * wr2[j])
                            + (nw[2] * wr3[j] + nw[3] * wr4[j])) + nw4 * nf[j];
                base[j] = fast_tanh(xn * we[j] + be[j]) + csv * ctxA;
            }
        }

        // --- P1: y[j,n] = sum_i W[j,i] v[n,i] via MFMA (all 8 waves) ---
        f32x4 a0a = z4, a0b = z4, a1a = z4, a1b = z4;
        #pragma unroll
        for (int kt = 0; kt < 4; ++kt) {
            bf16x8 bfr0 = *(const bf16x8*)(vsrc + kt * 32);
            bf16x8 bfr1 = *(const bf16x8*)(vsrc + (kt + 4) * 32);
            a0a = __builtin_amdgcn_mfma_f32_16x16x32_bf16(wfa[0][kt],     bfr0, a0a, 0, 0, 0);
            a1a = __builtin_amdgcn_mfma_f32_16x16x32_bf16(wfa[1][kt],     bfr0, a1a, 0, 0, 0);
            a0b = __builtin_amdgcn_mfma_f32_16x16x32_bf16(wfa[0][kt + 4], bfr1, a0b, 0, 0, 0);
            a1b = __builtin_amdgcn_mfma_f32_16x16x32_bf16(wfa[1][kt + 4], bfr1, a1b, 0, 0, 0);
        }
        if (bn < 2) {                 // D: row = quad*4+reg, col = bn
            f32x4 y0 = a0a + a0b, y1 = a1a + a1b;
            float* yb = s_y + bn * 256 + wave * 32 + quad * 4;
            *(f32x4*)yb        = y0;
            *(f32x4*)(yb + 16) = y1;
        }
        __syncthreads();   // [1] y visible

        // --- P2+P3 (waves 0/1 only): tanh + in-wave LN + v write ---
        if (wave < 2) {
            f32x4 yv = *(const f32x4*)(s_y + n * 256 + h0);
            f32x4 yt;
            #pragma unroll
            for (int j = 0; j < 4; ++j) yt[j] = fast_tanh(yv[j] + bu[j]);
            float ps1 = (yt[0] + yt[1]) + (yt[2] + yt[3]);
            float ps2 = (yt[0]*yt[0] + yt[1]*yt[1]) + (yt[2]*yt[2] + yt[3]*yt[3]);
            float S1 = wave_sum_all(ps1);
            float S2 = wave_sum_all(ps2);
            float mu   = S1 * (1.f / 256.f);
            float var  = S2 * (1.f / 256.f) - mu * mu;
            float rstd = rsqrtf(var + 1e-5f);
            bf16x4 vv;
            #pragma unroll
            for (int j = 0; j < 4; ++j) {
                hn[j] = (yt[j] - mu) * rstd * gm[j] + bt[j];
                vv[j] = (__bf16)(base[j] + coef * hn[j]);
            }
            *(bf16x4*)(s_v + n * 288 + h0) = vv;   // critical write ASAP

            // --- off-critical-path: window scatter+slide+retire+admit ---
            f32x4 ret;
            #pragma unroll
            for (int j = 0; j < 4; ++j) {
                ret[j] = wr0[j] + wt0 * hn[j];
                wr0[j] = wr1[j] + wt1 * hn[j];
                wr1[j] = wr2[j] + wt2 * hn[j];
                wr2[j] = wr3[j] + wt3 * hn[j];
                wr3[j] = wr4[j] + wt4 * hn[j];
                wr4[j] = nf[j];
            }
            *(f32x4*)(mcol + ((t - 2) & 63) * 256) = ret;   // retire slot t-2
            wt0 = nw[0]; wt1 = nw[1]; wt2 = nw[2]; wt3 = nw[3]; wt4 = nw4;
            // prefetch next step's inputs (same-thread mcol slot: no hazard;
            // last written at t-58, next write at t+6)
            nf = *(const f32x4*)(mcol + ((t + 4) & 63) * 256);
            {   const float* wp = s_wt + ((t + 2) & 63) * 8;
                nw  = *(const f32x4*)wp;
                nw4 = wp[4];
            }
            xn = s_x[n * 256 + ((t + 2) & 255)];
        }
        __syncthreads();   // [2] v visible
    }

    // --- epilogue: out[r0+n, o] = h . W_out[o,:] + b_out[o] (waves 0/1) ---
    if (wave < 2) {
        #pragma unroll
        for (int o = 0; o < 10; ++o) {
            f32x4 wo = *(const f32x4*)(W_out + o * 256 + h0);
            float p = (hn[0] * wo[0] + hn[1] * wo[1])
                    + (hn[2] * wo[2] + hn[3] * wo[3]);
            #pragma unroll
            for (int m = 32; m >= 1; m >>= 1) p += __shfl_xor(p, m, 64);
            if (lane == 0) out[(r0 + n) * 10 + o] = p + b_out[o];
        }
    }
}

extern "C" void kernel_launch(void* const* d_in, const int* in_sizes, int n_in,
                              void* d_out, int out_size, void* d_ws, size_t ws_size,
                              hipStream_t stream) {
    const float* x    = (const float*)d_in[0];
    const float* W_e  = (const float*)d_in[1];
    const float* b_e  = (const float*)d_in[2];
    const float* W_u  = (const float*)d_in[3];
    const float* b_u  = (const float*)d_in[4];
    const float* gmm  = (const float*)d_in[5];
    const float* bta  = (const float*)d_in[6];
    const float* W_o  = (const float*)d_in[7];
    const float* b_o  = (const float*)d_in[8];
    const float* cst  = (const float*)d_in[9];
    float* out = (float*)d_out;

    (void)hipFuncSetAttribute(reinterpret_cast<const void*>(postnorm_kernel),
                              hipFuncAttributeMaxDynamicSharedMemorySize,
                              SMEM_BYTES);

    postnorm_kernel<<<dim3(256), dim3(512), SMEM_BYTES, stream>>>(
        x, W_e, b_e, W_u, b_u, gmm, bta, W_o, b_o, cst, out);
}

// Round 7
// 359.238 us; speedup vs baseline: 1.0122x; 1.0122x over previous
//
#include <hip/hip_runtime.h>

// PostNormBoth: T=256-step recurrence, B=512 independent chains, H=256.
// R8 = R7 with the compile fix (_Float16 instead of __half; no extra header).
// R4 chassis (256 blocks x 512 thr, 2 rows/block, 3 barriers/step,
// 8-wave-spread P2/P3 — best measured: 287us) with ONE change:
//   memory slots stored as fp16 (_Float16) instead of f32.
//   |slot| <= ~2 and each slot is rounded exactly once per lifetime
//   (window accumulates in f32 registers; store at retire, read 59 steps
//   later) -> added error ~5e-4, negligible vs passing absmax 0.0117.
//   s_mem 128KB -> 64KB, SMEM 138KB -> 71.3KB  ==> 2 workgroups/CU.
//   Two unsynchronized blocks interleave: one block's barrier drains and
//   LDS-latency stalls are filled by the other block's MFMA/VALU issue.
//   __launch_bounds__(512,4) caps VGPR at 128 to guarantee co-residency.

#define TT 256

typedef __bf16 bf16x8 __attribute__((ext_vector_type(8)));
typedef float  f32x4  __attribute__((ext_vector_type(4)));

__device__ __forceinline__ float fast_tanh(float x) {
    float e = __expf(2.f * x);
    return 1.f - __fdividef(2.f, e + 1.f);
}

// v += dpp(v); CTRL/RM compile-time. old=0 + bound_ctrl so masked lanes add 0.
template<int CTRL, int RM>
__device__ __forceinline__ float dpp_add(float v) {
    int t = __builtin_amdgcn_update_dpp(0, __float_as_int(v), CTRL, RM, 0xf, true);
    return v + __int_as_float(t);
}
// full 64-lane sum; valid in lane 63.
__device__ __forceinline__ float wave_sum63(float v) {
    v = dpp_add<0xB1,  0xf>(v);   // quad_perm xor1
    v = dpp_add<0x4E,  0xf>(v);   // quad_perm xor2
    v = dpp_add<0x141, 0xf>(v);   // row_half_mirror (8-group)
    v = dpp_add<0x140, 0xf>(v);   // row_mirror (16-group)
    v = dpp_add<0x142, 0xa>(v);   // row_bcast15 -> rows 1,3
    v = dpp_add<0x143, 0xc>(v);   // row_bcast31 -> rows 2,3
    return v;
}

// ---- dynamic LDS layout (bytes) ----
// s_mem  [2][64][256] f16 :     0  (65536)
// s_x    [2][256]     f32 : 65536  (2048)
// s_y    [2][256]     f32 : 67584  (2048)
// s_v    [2][288]     bf16: 69632  (1152)
// s_red1 [8]          f32 : 70784  (32)
// s_red2 [8]          f32 : 70816  (32)
// s_wt   [64][8]      f32 : 70848  (2048)
// s_oacc [20]         f32 : 72896  (80)
#define SMEM_BYTES 72976

__global__ __launch_bounds__(512, 4)
void postnorm_kernel(const float* __restrict__ x,
                     const float* __restrict__ W_embed,
                     const float* __restrict__ b_embed,
                     const float* __restrict__ W_update,
                     const float* __restrict__ b_update,
                     const float* __restrict__ gamma,
                     const float* __restrict__ beta,
                     const float* __restrict__ W_out,
                     const float* __restrict__ b_out,
                     const float* __restrict__ ctx_s,
                     float* __restrict__ out)
{
    extern __shared__ __align__(16) char smem[];
    _Float16* s_mem  = (_Float16*)(smem);
    float*  s_x    = (float*)(smem + 65536);
    float*  s_y    = (float*)(smem + 67584);
    __bf16* s_v    = (__bf16*)(smem + 69632);
    float*  s_red1 = (float*)(smem + 70784);
    float*  s_red2 = (float*)(smem + 70816);
    float*  s_wt   = (float*)(smem + 70848);
    float*  s_oacc = (float*)(smem + 72896);

    const int tid  = threadIdx.x;
    const int n    = tid >> 8;      // batch row within block (0..1)
    const int i    = tid & 255;     // hidden index
    const int wave = tid >> 6;      // wave w owns W rows [32w,32w+32)
    const int lane = tid & 63;
    const int bn   = lane & 15;     // MFMA col; real batch only for <2
    const int quad = lane >> 4;
    const int r0   = blockIdx.x * 2;

    // ---- init (zero 64KB of slot memory: 512 thr x 8 x 16B) ----
    {   f32x4 z = {0.f, 0.f, 0.f, 0.f};
        f32x4* p = (f32x4*)s_mem;
        #pragma unroll
        for (int k = 0; k < 8; ++k) p[tid + k * 512] = z;
    }
    s_x[tid] = x[(r0 + n) * TT + i];
    if (tid < 20) s_oacc[tid] = 0.f;

    // weight table: pointer is t&63 for all rows; row padded to 8 floats
    if (tid < 64) {
        float wv[5]; float ssum = 0.f;
        #pragma unroll
        for (int k = 0; k < 5; ++k) {
            int idx = (tid + k - 2) & 63;            // wrapped index
            float d = (float)idx - (float)tid;       // delta AFTER wrap
            wv[k] = expf(-(d * d) * 0.125f);         // TAU=8
            ssum += wv[k];
        }
        #pragma unroll
        for (int k = 0; k < 5; ++k) s_wt[tid * 8 + k] = wv[k] / ssum;
    }

    const float we  = W_embed[i];
    const float be  = b_embed[i];
    const float bu  = b_update[i];
    const float gm  = gamma[i];
    const float btt = beta[i];
    const float csv = 1.f / (1.f + expf(-ctx_s[0]));

    // ---- W_update -> bf16 MFMA A-fragments resident in VGPRs ----
    bf16x8 wfa[2][8];
    #pragma unroll
    for (int mt = 0; mt < 2; ++mt) {
        #pragma unroll
        for (int kt = 0; kt < 8; ++kt) {
            const float* wp = W_update + (wave * 32 + mt * 16 + bn) * 256
                                       + kt * 32 + quad * 8;
            f32x4 a = *(const f32x4*)wp;
            f32x4 b = *(const f32x4*)(wp + 4);
            bf16x8 f;
            f[0] = (__bf16)a[0]; f[1] = (__bf16)a[1];
            f[2] = (__bf16)a[2]; f[3] = (__bf16)a[3];
            f[4] = (__bf16)b[0]; f[5] = (__bf16)b[1];
            f[6] = (__bf16)b[2]; f[7] = (__bf16)b[3];
            wfa[mt][kt] = f;
        }
    }

    __syncthreads();
    {   // v(t=0): memory==0, h==0 -> v = inp
        float inp0 = fast_tanh(s_x[n * 256] * we + be);
        s_v[n * 288 + i] = (__bf16)inp0;
    }

    // attention weights for pointer 0 + prefetched step-0 P3 inputs
    float wt0, wt1, wt2, wt3, wt4;
    {   f32x4 wv = *(const f32x4*)(s_wt);
        wt0 = wv[0]; wt1 = wv[1]; wt2 = wv[2]; wt3 = wv[3]; wt4 = s_wt[4];
    }
    f32x4 nw  = *(const f32x4*)(s_wt + 8);       // weights for pointer 1
    float nw4 = s_wt[8 + 4];
    float xn  = s_x[n * 256 + 1];                // x[t+1]
    float nf  = 0.f;                             // admit slot 3 (zero-init)
    __syncthreads();

    float hn = 0.f;
    // register window: slots (t-2..t+2) mod 64 of memory column (n,i)
    float w0 = 0.f, w1 = 0.f, w2 = 0.f, w3 = 0.f, w4 = 0.f;
    _Float16* mcol = s_mem + (n << 14) + i;      // row stride 16384 halves
    // broadcast B-frag source; row stride 288 bf16 = 576B -> banks disjoint
    const __bf16* vsrc = s_v + (bn & 1) * 288 + quad * 8;

    #pragma unroll 1
    for (int t = 0; t < TT; ++t) {
        // input embed for v(t+1): independent of this step -> hides under P1
        float inp = fast_tanh(xn * we + be);

        // --- P1: y[j,n] = sum_i W[j,i] v[n,i] via MFMA ---
        f32x4 a0a = {0,0,0,0}, a0b = {0,0,0,0}, a1a = {0,0,0,0}, a1b = {0,0,0,0};
        #pragma unroll
        for (int kt = 0; kt < 4; ++kt) {
            bf16x8 bfr0 = *(const bf16x8*)(vsrc + kt * 32);
            bf16x8 bfr1 = *(const bf16x8*)(vsrc + (kt + 4) * 32);
            a0a = __builtin_amdgcn_mfma_f32_16x16x32_bf16(wfa[0][kt],     bfr0, a0a, 0, 0, 0);
            a1a = __builtin_amdgcn_mfma_f32_16x16x32_bf16(wfa[1][kt],     bfr0, a1a, 0, 0, 0);
            a0b = __builtin_amdgcn_mfma_f32_16x16x32_bf16(wfa[0][kt + 4], bfr1, a0b, 0, 0, 0);
            a1b = __builtin_amdgcn_mfma_f32_16x16x32_bf16(wfa[1][kt + 4], bfr1, a1b, 0, 0, 0);
        }
        if (bn < 2) {                 // D: row = quad*4+reg, col = bn
            f32x4 y0 = a0a + a0b, y1 = a1a + a1b;
            float* yb = s_y + bn * 256 + wave * 32 + quad * 4;
            *(f32x4*)yb        = y0;
            *(f32x4*)(yb + 16) = y1;
        }
        __syncthreads();

        // --- P2: bias + tanh + LN stats via DPP ---
        float yt = fast_tanh(s_y[tid] + bu);
        float s1 = wave_sum63(yt);
        float s2 = wave_sum63(yt * yt);
        if (lane == 63) { s_red1[wave] = s1; s_red2[wave] = s2; }
        __syncthreads();

        // --- P3: LN finalize + register-window scatter/gather ---
        f32x4 r1 = *(const f32x4*)(s_red1 + n * 4);
        f32x4 r2 = *(const f32x4*)(s_red2 + n * 4);
        float S1 = (r1[0] + r1[1]) + (r1[2] + r1[3]);
        float S2 = (r2[0] + r2[1]) + (r2[2] + r2[3]);
        float mu   = S1 * (1.f / 256.f);
        float var  = S2 * (1.f / 256.f) - mu * mu;
        float rstd = rsqrtf(var + 1e-5f);
        hn = (yt - mu) * rstd * gm + btt;

        // scatter with pointer-t weights (positional: w0 = slot t-2)
        w0 += wt0 * hn; w1 += wt1 * hn; w2 += wt2 * hn;
        w3 += wt3 * hn; w4 += wt4 * hn;

        // slide window: retire slot t-2 (single fp16 round), admit slot t+3
        mcol[((t - 2) & 63) << 8] = (_Float16)w0;
        w0 = w1; w1 = w2; w2 = w3; w3 = w4; w4 = nf;
        float ctx = ((nw[0] * w0 + nw[1] * w1) + (nw[2] * w2 + nw[3] * w3))
                  + nw4 * w4;
        float v = inp + csv * ctx + hn;
        s_v[n * 288 + i] = (__bf16)v;
        wt0 = nw[0]; wt1 = nw[1]; wt2 = nw[2]; wt3 = nw[3]; wt4 = nw4;

        // prefetch next step's P3 inputs; loop-end barrier drain covers
        // their latency. mcol slot (t+4)&63 is same-thread-only (last
        // written at step t-58, next write at t+6) -> no cross-thread hazard.
        nf  = (float)mcol[((t + 4) & 63) << 8];
        {   const float* wp = s_wt + ((t + 2) & 63) * 8;
            nw  = *(const f32x4*)wp;
            nw4 = wp[4];
        }
        xn  = s_x[n * 256 + ((t + 2) & 255)];
        __syncthreads();
    }

    // --- epilogue: out[r0+n, o] = h . W_out[o,:] + b_out[o] ---
    #pragma unroll
    for (int o = 0; o < 10; ++o) {
        float p = hn * W_out[o * 256 + i];
        #pragma unroll
        for (int m = 32; m >= 1; m >>= 1) p += __shfl_xor(p, m, 64);
        if (lane == 0) atomicAdd(&s_oacc[n * 10 + o], p);
    }
    __syncthreads();
    if (tid < 20) {
        int nn = tid / 10, o = tid % 10;
        out[(r0 + nn) * 10 + o] = s_oacc[tid] + b_out[o];
    }
}

extern "C" void kernel_launch(void* const* d_in, const int* in_sizes, int n_in,
                              void* d_out, int out_size, void* d_ws, size_t ws_size,
                              hipStream_t stream) {
    const float* x    = (const float*)d_in[0];
    const float* W_e  = (const float*)d_in[1];
    const float* b_e  = (const float*)d_in[2];
    const float* W_u  = (const float*)d_in[3];
    const float* b_u  = (const float*)d_in[4];
    const float* gmm  = (const float*)d_in[5];
    const float* bta  = (const float*)d_in[6];
    const float* W_o  = (const float*)d_in[7];
    const float* b_o  = (const float*)d_in[8];
    const float* cst  = (const float*)d_in[9];
    float* out = (float*)d_out;

    (void)hipFuncSetAttribute(reinterpret_cast<const void*>(postnorm_kernel),
                              hipFuncAttributeMaxDynamicSharedMemorySize,
                              SMEM_BYTES);

    postnorm_kernel<<<dim3(256), dim3(512), SMEM_BYTES, stream>>>(
        x, W_e, b_e, W_u, b_u, gmm, bta, W_o, b_o, cst, out);
}

// Round 8
// 310.732 us; speedup vs baseline: 1.1702x; 1.1561x over previous
//
#include <hip/hip_runtime.h>

// PostNormBoth: T=256-step recurrence, B=512 chains, H=256.
// R9: latency-bound conclusion (R2/R8: co-residency doesn't help; R6: wave-
// concentration doesn't help) -> shorten the serial chain. The s_y
// redistribution (write y + barrier + read y) is DELETED: since B-cols
// replicate v by bn&1, every lane already holds y[wave*32+mt*16+quad*4+r]
// for row bn&1 in its accumulators. Ownership is re-mapped to match:
//   b = bn>>1, row = bn&1, i_own = wave*32 + (b>>2)*16 + quad*4 + (b&3)
// (bijective over 512 threads x {row,i}). Per step: select owned y from
// regs (7 cndmask) -> tanh -> parity-preserving xor-reduce (DPP xor2,
// ds_swizzle xor4/8/16, shfl xor32; bit0=row never crossed) -> tiny s_red
// exchange -> barrier -> LN -> window -> v-write -> barrier.
// 2 barriers/step, no wide LDS roundtrip on the critical chain.

#define TT 256

typedef __bf16 bf16x8 __attribute__((ext_vector_type(8)));
typedef float  f32x4  __attribute__((ext_vector_type(4)));

__device__ __forceinline__ float fast_tanh(float x) {
    float e = __expf(2.f * x);
    return 1.f - __fdividef(2.f, e + 1.f);
}

// v += dpp(v); old=0 + bound_ctrl so masked lanes add 0.
template<int CTRL, int RM>
__device__ __forceinline__ float dpp_add(float v) {
    int t = __builtin_amdgcn_update_dpp(0, __float_as_int(v), CTRL, RM, 0xf, true);
    return v + __int_as_float(t);
}
// v += swizzle(v) with compile-time BitMode pattern.
template<int IMM>
__device__ __forceinline__ float swz_add(float v) {
    int t = __builtin_amdgcn_ds_swizzle(__float_as_int(v), IMM);
    return v + __int_as_float(t);
}

// ---- dynamic LDS layout (bytes) ----
// s_mem  [2][64][256] f32 :      0  (131072)
// s_x    [2][256]     f32 : 131072  (2048)
// s_v    [2][288]     bf16: 133120  (1152)
// s_red1 [2][8]       f32 : 134272  (64)
// s_red2 [2][8]       f32 : 134336  (64)
// s_wt   [64][8]      f32 : 134400  (2048)
// s_oacc [20]         f32 : 136448  (80)
#define SMEM_BYTES 136528

__global__ __launch_bounds__(512, 2)
void postnorm_kernel(const float* __restrict__ x,
                     const float* __restrict__ W_embed,
                     const float* __restrict__ b_embed,
                     const float* __restrict__ W_update,
                     const float* __restrict__ b_update,
                     const float* __restrict__ gamma,
                     const float* __restrict__ beta,
                     const float* __restrict__ W_out,
                     const float* __restrict__ b_out,
                     const float* __restrict__ ctx_s,
                     float* __restrict__ out)
{
    extern __shared__ __align__(16) char smem[];
    float*  s_mem  = (float*)(smem);
    float*  s_x    = (float*)(smem + 131072);
    __bf16* s_v    = (__bf16*)(smem + 133120);
    float*  s_red1 = (float*)(smem + 134272);
    float*  s_red2 = (float*)(smem + 134336);
    float*  s_wt   = (float*)(smem + 134400);
    float*  s_oacc = (float*)(smem + 136448);

    const int tid  = threadIdx.x;
    const int wave = tid >> 6;       // wave w owns W rows [32w,32w+32)
    const int lane = tid & 63;
    const int bn   = lane & 15;      // MFMA col
    const int quad = lane >> 4;
    const int r0   = blockIdx.x * 2;

    // ownership: this lane's accumulators hold y[i_own] for row `row`
    const int b     = bn >> 1;
    const int row   = bn & 1;
    const int i_own = wave * 32 + (b >> 2) * 16 + quad * 4 + (b & 3);

    // ---- init ----
    {   f32x4 z = {0.f, 0.f, 0.f, 0.f};
        f32x4* p = (f32x4*)s_mem;
        #pragma unroll
        for (int k = 0; k < 16; ++k) p[tid + k * 512] = z;
    }
    s_x[tid] = x[(r0 + (tid >> 8)) * TT + (tid & 255)];
    if (tid < 20) s_oacc[tid] = 0.f;

    // weight table: pointer is t&63; row padded to 8 floats
    if (tid < 64) {
        float wv[5]; float ssum = 0.f;
        #pragma unroll
        for (int k = 0; k < 5; ++k) {
            int idx = (tid + k - 2) & 63;            // wrapped index
            float d = (float)idx - (float)tid;       // delta AFTER wrap
            wv[k] = expf(-(d * d) * 0.125f);         // TAU=8
            ssum += wv[k];
        }
        #pragma unroll
        for (int k = 0; k < 5; ++k) s_wt[tid * 8 + k] = wv[k] / ssum;
    }

    // per-owned-i params
    const float we  = W_embed[i_own];
    const float be  = b_embed[i_own];
    const float bu  = b_update[i_own];
    const float gm  = gamma[i_own];
    const float btt = beta[i_own];
    const float csv = 1.f / (1.f + expf(-ctx_s[0]));

    // ---- W_update -> bf16 MFMA A-fragments resident in VGPRs ----
    bf16x8 wfa[2][8];
    #pragma unroll
    for (int mt = 0; mt < 2; ++mt) {
        #pragma unroll
        for (int kt = 0; kt < 8; ++kt) {
            const float* wp = W_update + (wave * 32 + mt * 16 + bn) * 256
                                       + kt * 32 + quad * 8;
            f32x4 a = *(const f32x4*)wp;
            f32x4 bb = *(const f32x4*)(wp + 4);
            bf16x8 f;
            f[0] = (__bf16)a[0];  f[1] = (__bf16)a[1];
            f[2] = (__bf16)a[2];  f[3] = (__bf16)a[3];
            f[4] = (__bf16)bb[0]; f[5] = (__bf16)bb[1];
            f[6] = (__bf16)bb[2]; f[7] = (__bf16)bb[3];
            wfa[mt][kt] = f;
        }
    }

    __syncthreads();
    {   // v(t=0): memory==0, h==0 -> v = inp (one write per owned (row,i))
        float inp0 = fast_tanh(s_x[row * 256] * we + be);
        s_v[row * 288 + i_own] = (__bf16)inp0;
    }

    // attention weights for pointer 0 + step-0 prefetches
    float wt0, wt1, wt2, wt3, wt4;
    {   f32x4 wv = *(const f32x4*)(s_wt);
        wt0 = wv[0]; wt1 = wv[1]; wt2 = wv[2]; wt3 = wv[3]; wt4 = s_wt[4];
    }
    f32x4 nw  = *(const f32x4*)(s_wt + 8);       // weights for pointer 1
    float nw4 = s_wt[8 + 4];
    float xn  = s_x[row * 256 + 1];              // x[t+1] for own row
    float nf  = 0.f;                             // admit slot 3 (zero-init)
    __syncthreads();

    float hn = 0.f;
    // register window: slots (t-2..t+2) mod 64 of memory column (row,i_own)
    float w0 = 0.f, w1 = 0.f, w2 = 0.f, w3 = 0.f, w4 = 0.f;
    float* mcol = s_mem + (row << 14) + i_own;
    // broadcast B-frag source; row stride 288 bf16 keeps rows bank-disjoint
    const __bf16* vsrc = s_v + row * 288 + quad * 8;

    #pragma unroll 1
    for (int t = 0; t < TT; ++t) {
        // input embed for v(t+1): independent of this step -> hides under P1
        float inp = fast_tanh(xn * we + be);

        // --- P1: y = W . v via MFMA; D col bn carries row bn&1 ---
        f32x4 a0a = {0,0,0,0}, a0b = {0,0,0,0}, a1a = {0,0,0,0}, a1b = {0,0,0,0};
        #pragma unroll
        for (int kt = 0; kt < 4; ++kt) {
            bf16x8 bfr0 = *(const bf16x8*)(vsrc + kt * 32);
            bf16x8 bfr1 = *(const bf16x8*)(vsrc + (kt + 4) * 32);
            a0a = __builtin_amdgcn_mfma_f32_16x16x32_bf16(wfa[0][kt],     bfr0, a0a, 0, 0, 0);
            a1a = __builtin_amdgcn_mfma_f32_16x16x32_bf16(wfa[1][kt],     bfr0, a1a, 0, 0, 0);
            a0b = __builtin_amdgcn_mfma_f32_16x16x32_bf16(wfa[0][kt + 4], bfr1, a0b, 0, 0, 0);
            a1b = __builtin_amdgcn_mfma_f32_16x16x32_bf16(wfa[1][kt + 4], bfr1, a1b, 0, 0, 0);
        }

        // --- select owned y from regs (no LDS): (mt,r) = (b>>2, b&3) ---
        f32x4 y0 = a0a + a0b, y1 = a1a + a1b;
        f32x4 ym = (b & 4) ? y1 : y0;
        float yA = (b & 2) ? ym[2] : ym[0];
        float yB = (b & 2) ? ym[3] : ym[1];
        float ysel = (b & 1) ? yB : yA;

        // --- P2: tanh + LN stats; xor-reduce over 32 same-row lanes ---
        float yt = fast_tanh(ysel + bu);
        float s1 = yt, s2 = yt * yt;
        s1 = dpp_add<0x4E, 0xf>(s1);  s2 = dpp_add<0x4E, 0xf>(s2);  // xor2
        s1 = swz_add<0x101F>(s1);     s2 = swz_add<0x101F>(s2);     // xor4
        s1 = swz_add<0x201F>(s1);     s2 = swz_add<0x201F>(s2);     // xor8
        s1 = swz_add<0x401F>(s1);     s2 = swz_add<0x401F>(s2);     // xor16
        s1 += __shfl_xor(s1, 32, 64); s2 += __shfl_xor(s2, 32, 64); // xor32
        if (lane < 2) {  // lane0 = row0 partial, lane1 = row1 partial
            s_red1[lane * 8 + wave] = s1;
            s_red2[lane * 8 + wave] = s2;
        }
        __syncthreads();   // [1] partials visible (also fences vsrc reads)

        // --- P3: LN finalize + window + v ---
        f32x4 r1a = *(const f32x4*)(s_red1 + row * 8);
        f32x4 r1b = *(const f32x4*)(s_red1 + row * 8 + 4);
        f32x4 r2a = *(const f32x4*)(s_red2 + row * 8);
        f32x4 r2b = *(const f32x4*)(s_red2 + row * 8 + 4);
        float S1 = ((r1a[0] + r1a[1]) + (r1a[2] + r1a[3]))
                 + ((r1b[0] + r1b[1]) + (r1b[2] + r1b[3]));
        float S2 = ((r2a[0] + r2a[1]) + (r2a[2] + r2a[3]))
                 + ((r2b[0] + r2b[1]) + (r2b[2] + r2b[3]));
        float mu   = S1 * (1.f / 256.f);
        float var  = S2 * (1.f / 256.f) - mu * mu;
        float rstd = rsqrtf(var + 1e-5f);
        hn = (yt - mu) * rstd * gm + btt;

        // scatter with pointer-t weights (positional: w0 = slot t-2)
        w0 += wt0 * hn; w1 += wt1 * hn; w2 += wt2 * hn;
        w3 += wt3 * hn; w4 += wt4 * hn;

        // slide window: retire slot t-2, admit slot t+3 (prefetched)
        mcol[((t - 2) & 63) << 8] = w0;
        w0 = w1; w1 = w2; w2 = w3; w3 = w4; w4 = nf;
        float ctx = ((nw[0] * w0 + nw[1] * w1) + (nw[2] * w2 + nw[3] * w3))
                  + nw4 * w4;
        float v = inp + csv * ctx + hn;
        s_v[row * 288 + i_own] = (__bf16)v;
        wt0 = nw[0]; wt1 = nw[1]; wt2 = nw[2]; wt3 = nw[3]; wt4 = nw4;

        // prefetch next step's P3 inputs; loop-end barrier covers latency.
        // mcol slot (t+4)&63 is same-thread-only -> no cross-thread hazard.
        nf  = mcol[((t + 4) & 63) << 8];
        {   const float* wp = s_wt + ((t + 2) & 63) * 8;
            nw  = *(const f32x4*)wp;
            nw4 = wp[4];
        }
        xn  = s_x[row * 256 + ((t + 2) & 255)];
        __syncthreads();   // [2] v visible
    }

    // --- epilogue: stage hn into s_x (reuse) to restore tid-order ---
    s_x[row * 256 + i_own] = hn;
    __syncthreads();
    {
        const int n = tid >> 8, i = tid & 255;
        float h = s_x[tid];
        #pragma unroll
        for (int o = 0; o < 10; ++o) {
            float p = h * W_out[o * 256 + i];
            #pragma unroll
            for (int m = 32; m >= 1; m >>= 1) p += __shfl_xor(p, m, 64);
            if (lane == 0) atomicAdd(&s_oacc[n * 10 + o], p);
        }
    }
    __syncthreads();
    if (tid < 20) {
        int nn = tid / 10, o = tid % 10;
        out[(r0 + nn) * 10 + o] = s_oacc[tid] + b_out[o];
    }
}

extern "C" void kernel_launch(void* const* d_in, const int* in_sizes, int n_in,
                              void* d_out, int out_size, void* d_ws, size_t ws_size,
                              hipStream_t stream) {
    const float* x    = (const float*)d_in[0];
    const float* W_e  = (const float*)d_in[1];
    const float* b_e  = (const float*)d_in[2];
    const float* W_u  = (const float*)d_in[3];
    const float* b_u  = (const float*)d_in[4];
    const float* gmm  = (const float*)d_in[5];
    const float* bta  = (const float*)d_in[6];
    const float* W_o  = (const float*)d_in[7];
    const float* b_o  = (const float*)d_in[8];
    const float* cst  = (const float*)d_in[9];
    float* out = (float*)d_out;

    (void)hipFuncSetAttribute(reinterpret_cast<const void*>(postnorm_kernel),
                              hipFuncAttributeMaxDynamicSharedMemorySize,
                              SMEM_BYTES);

    postnorm_kernel<<<dim3(256), dim3(512), SMEM_BYTES, stream>>>(
        x, W_e, b_e, W_u, b_u, gmm, bta, W_o, b_o, cst, out);
}